// Round 2
// baseline (1131.033 us; speedup 1.0000x reference)
//
#include <hip/hip_runtime.h>

#define B_SZ 2048
#define D_SZ 128
#define H_SZ 512

typedef _Float16 half8 __attribute__((ext_vector_type(8)));
typedef float floatx4 __attribute__((ext_vector_type(4)));

static __device__ __forceinline__ float tanh_fast(float x) {
  // tanh(x) = 1 - 2/(e^{2x}+1); exact identity, saturates correctly at +-inf
  float e = __expf(2.0f * x);
  return 1.0f - 2.0f * __builtin_amdgcn_rcpf(e + 1.0f);
}

// Split two f32 into fp16 hi + fp16 lo (RTZ), packed as u32 each.
// a ~= hi + lo to ~22 mantissa bits.
static __device__ __forceinline__ void split_pair(float a, float b,
                                                  unsigned int& hi,
                                                  unsigned int& lo) {
  auto h = __builtin_amdgcn_cvt_pkrtz(a, b);     // __fp16 x2
  float ra = a - (float)h[0];
  float rb = b - (float)h[1];
  auto l = __builtin_amdgcn_cvt_pkrtz(ra, rb);
  hi = __builtin_bit_cast(unsigned int, h);
  lo = __builtin_bit_cast(unsigned int, l);
}

// ---------------- Encoder: z[j][b] = tanh(leaky(x@We1^T+be1)@We2^T+be2)^T ---
// fp32 vector math (errors here are amplified by sqrt(128) cumsum, keep exact).
// 256 blocks x 256 threads, 8 batch rows per block.
__global__ __launch_bounds__(256) void enc_kernel(
    const float* __restrict__ x, const float* __restrict__ We1,
    const float* __restrict__ be1, const float* __restrict__ We2,
    const float* __restrict__ be2, float* __restrict__ z) {
  __shared__ float xs[8][132];   // +4 pad breaks bank alignment
  __shared__ float hs[8][516];
  const int t = threadIdx.x;
  const int b0 = blockIdx.x * 8;
  {
    int r = t >> 5, c4 = t & 31;
    float4 v = ((const float4*)(x + (size_t)(b0 + r) * D_SZ))[c4];
    xs[r][c4 * 4 + 0] = v.x; xs[r][c4 * 4 + 1] = v.y;
    xs[r][c4 * 4 + 2] = v.z; xs[r][c4 * 4 + 3] = v.w;
  }
  __syncthreads();
  // enc_h: thread owns h = t, t+256 across all 8 rows
  for (int hb = 0; hb < 2; ++hb) {
    const int h = t + hb * 256;
    float acc[8];
    float bias = be1[h];
#pragma unroll
    for (int r = 0; r < 8; ++r) acc[r] = bias;
    const float4* wp = (const float4*)(We1 + (size_t)h * D_SZ);
    for (int k4 = 0; k4 < 32; ++k4) {
      float4 wv = wp[k4];
#pragma unroll
      for (int r = 0; r < 8; ++r) {
        acc[r] = fmaf(wv.x, xs[r][k4 * 4 + 0], acc[r]);
        acc[r] = fmaf(wv.y, xs[r][k4 * 4 + 1], acc[r]);
        acc[r] = fmaf(wv.z, xs[r][k4 * 4 + 2], acc[r]);
        acc[r] = fmaf(wv.w, xs[r][k4 * 4 + 3], acc[r]);
      }
    }
#pragma unroll
    for (int r = 0; r < 8; ++r) {
      float u = acc[r];
      hs[r][h] = (u >= 0.0f) ? u : 0.2f * u;   // leaky 0.2
    }
  }
  __syncthreads();
  // encoded: thread owns one d, 4 rows; store transposed z[d][b]
  {
    const int d = t & 127, rg = t >> 7;
    float acc[4];
    float bias = be2[d];
#pragma unroll
    for (int r = 0; r < 4; ++r) acc[r] = bias;
    const float4* wp = (const float4*)(We2 + (size_t)d * H_SZ);
    for (int k4 = 0; k4 < 128; ++k4) {
      float4 wv = wp[k4];
#pragma unroll
      for (int r = 0; r < 4; ++r) {
        int row = rg * 4 + r;
        acc[r] = fmaf(wv.x, hs[row][k4 * 4 + 0], acc[r]);
        acc[r] = fmaf(wv.y, hs[row][k4 * 4 + 1], acc[r]);
        acc[r] = fmaf(wv.z, hs[row][k4 * 4 + 2], acc[r]);
        acc[r] = fmaf(wv.w, hs[row][k4 * 4 + 3], acc[r]);
      }
    }
#pragma unroll
    for (int r = 0; r < 4; ++r) {
      z[(size_t)d * B_SZ + b0 + rg * 4 + r] = tanh_fast(acc[r]);
    }
  }
}

// ---------------- Decoder bank + cumsum + tanh -----------------------------
// out[j,b,d] = tanh( sum_{j'<=j} ( hid[j',b,:] . W2s[j',d,:] + b2s[j',d] ) )
// hid[j,b,h] = leaky(z[j,b]*W1s[j,h] + b1s[j,h]) computed on the fly.
// 3-pass fp16 split MFMA (ah*bh + ah*bl + al*bh) for fp32-grade precision.
// Grid 256 blocks (Bt=32 x Dt=32), 256 threads (4 waves, one 16x16 frag each).
__global__ __launch_bounds__(256, 1) void dec_kernel(
    const float* __restrict__ W1s, const float* __restrict__ b1s,
    const float* __restrict__ W2s, const float* __restrict__ b2s,
    const float* __restrict__ z, float* __restrict__ out) {
  // double-buffered K-chunk staging; rows padded 64+4 halves -> 68 uints
  __shared__ unsigned int Ah[2][32 * 68], Al[2][32 * 68];
  __shared__ unsigned int Bh[2][32 * 68], Bl[2][32 * 68];
  __shared__ float zsh[128 * 32];

  const int t = threadIdx.x;
  const int bx = blockIdx.x;
  // XCD swizzle: the 64 blocks sharing a d-tile land on a fixed XCD pair
  const int xcd = bx & 7;
  const int grp = bx >> 3;
  const int dt = xcd >> 1;                 // 0..3
  const int bt = grp * 2 + (xcd & 1);      // 0..63
  const int b0 = bt * 32, d0 = dt * 32;

  // one-time: z for all 128 j, this block's 32 b's
  for (int ii = 0; ii < 16; ++ii) {
    int e = t + 256 * ii;
    zsh[e] = z[(size_t)(e >> 5) * B_SZ + b0 + (e & 31)];
  }
  __syncthreads();

  const int lane = t & 63, w = t >> 6;
  const int wm = w >> 1, wn = w & 1;       // wave's fragment position
  const int quad = lane >> 4, l16 = lane & 15;
  const int g = t & 7, rr = t >> 3;        // staging: 8 threads/row, 32 rows

  floatx4 acc0 = {0.f, 0.f, 0.f, 0.f};     // ah*bh chain
  floatx4 acc1 = {0.f, 0.f, 0.f, 0.f};     // ah*bl chain
  floatx4 acc2 = {0.f, 0.f, 0.f, 0.f};     // al*bh chain

  const int st_off = rr * 68 + g * 8;              // staging store (uints)
  const int a_row = (wm * 16 + l16) * 68;          // frag read rows
  const int b_row = (wn * 16 + l16) * 68;

  for (int j = 0; j < 128; ++j) {
    const float* w1r = W1s + (size_t)j * H_SZ;
    const float* b1r = b1s + (size_t)j * H_SZ;
    const float* w2r = W2s + ((size_t)j * D_SZ + d0 + rr) * H_SZ;
    const float zv = zsh[j * 32 + rr];

#pragma unroll
    for (int kc = 0; kc < 4; ++kc) {
      const int buf = kc & 1;
      const int hb = kc * 128 + g * 16;   // 16 consecutive h per thread
      float w2v[16], w1v[16], b1v[16];
      *(float4*)&w2v[0]  = *(const float4*)(w2r + hb + 0);
      *(float4*)&w2v[4]  = *(const float4*)(w2r + hb + 4);
      *(float4*)&w2v[8]  = *(const float4*)(w2r + hb + 8);
      *(float4*)&w2v[12] = *(const float4*)(w2r + hb + 12);
      *(float4*)&w1v[0]  = *(const float4*)(w1r + hb + 0);
      *(float4*)&w1v[4]  = *(const float4*)(w1r + hb + 4);
      *(float4*)&w1v[8]  = *(const float4*)(w1r + hb + 8);
      *(float4*)&w1v[12] = *(const float4*)(w1r + hb + 12);
      *(float4*)&b1v[0]  = *(const float4*)(b1r + hb + 0);
      *(float4*)&b1v[4]  = *(const float4*)(b1r + hb + 4);
      *(float4*)&b1v[8]  = *(const float4*)(b1r + hb + 8);
      *(float4*)&b1v[12] = *(const float4*)(b1r + hb + 12);

      float hidv[16];
#pragma unroll
      for (int e = 0; e < 16; ++e) {
        float u = fmaf(zv, w1v[e], b1v[e]);
        hidv[e] = (u >= 0.0f) ? u : 0.2f * u;
      }
      unsigned int ah[8], al[8], bh8[8], bl8[8];
#pragma unroll
      for (int p = 0; p < 8; ++p) {
        split_pair(hidv[2 * p], hidv[2 * p + 1], ah[p], al[p]);
        split_pair(w2v[2 * p], w2v[2 * p + 1], bh8[p], bl8[p]);
      }
      ((uint4*)&Ah[buf][st_off])[0] = make_uint4(ah[0], ah[1], ah[2], ah[3]);
      ((uint4*)&Ah[buf][st_off + 4])[0] = make_uint4(ah[4], ah[5], ah[6], ah[7]);
      ((uint4*)&Al[buf][st_off])[0] = make_uint4(al[0], al[1], al[2], al[3]);
      ((uint4*)&Al[buf][st_off + 4])[0] = make_uint4(al[4], al[5], al[6], al[7]);
      ((uint4*)&Bh[buf][st_off])[0] = make_uint4(bh8[0], bh8[1], bh8[2], bh8[3]);
      ((uint4*)&Bh[buf][st_off + 4])[0] = make_uint4(bh8[4], bh8[5], bh8[6], bh8[7]);
      ((uint4*)&Bl[buf][st_off])[0] = make_uint4(bl8[0], bl8[1], bl8[2], bl8[3]);
      ((uint4*)&Bl[buf][st_off + 4])[0] = make_uint4(bl8[4], bl8[5], bl8[6], bl8[7]);

      __syncthreads();   // single barrier per chunk (double-buffered)

#pragma unroll
      for (int s = 0; s < 4; ++s) {
        const int ko = s * 16 + quad * 4;  // uint offset: k = s*32 + quad*8
        half8 fa_h = *(const half8*)&Ah[buf][a_row + ko];
        half8 fa_l = *(const half8*)&Al[buf][a_row + ko];
        half8 fb_h = *(const half8*)&Bh[buf][b_row + ko];
        half8 fb_l = *(const half8*)&Bl[buf][b_row + ko];
        acc0 = __builtin_amdgcn_mfma_f32_16x16x32_f16(fa_h, fb_h, acc0, 0, 0, 0);
        acc1 = __builtin_amdgcn_mfma_f32_16x16x32_f16(fa_h, fb_l, acc1, 0, 0, 0);
        acc2 = __builtin_amdgcn_mfma_f32_16x16x32_f16(fa_l, fb_h, acc2, 0, 0, 0);
      }
      __syncthreads();   // frag reads done before next chunk reuses buffer
    }

    // epilogue for this j: add b2s[j,d], write tanh(cumulative sum)
    const float bv = b2s[(size_t)j * D_SZ + d0 + wn * 16 + l16];
    float* orow = out + ((size_t)j * B_SZ + b0 + wm * 16 + quad * 4) * D_SZ +
                  d0 + wn * 16 + l16;
#pragma unroll
    for (int r = 0; r < 4; ++r) {
      acc0[r] += bv;   // fold running bias into the hh chain
      float s = acc0[r] + acc1[r] + acc2[r];
      orow[(size_t)r * D_SZ] = tanh_fast(s);
    }
  }
}

extern "C" void kernel_launch(void* const* d_in, const int* in_sizes, int n_in,
                              void* d_out, int out_size, void* d_ws,
                              size_t ws_size, hipStream_t stream) {
  (void)in_sizes; (void)n_in; (void)out_size; (void)ws_size;
  const float* x   = (const float*)d_in[0];
  const float* We1 = (const float*)d_in[1];
  const float* be1 = (const float*)d_in[2];
  const float* We2 = (const float*)d_in[3];
  const float* be2 = (const float*)d_in[4];
  const float* W1s = (const float*)d_in[5];
  const float* b1s = (const float*)d_in[6];
  const float* W2s = (const float*)d_in[7];
  const float* b2s = (const float*)d_in[8];
  float* out = (float*)d_out;
  float* zws = (float*)d_ws;  // D*B floats = 1 MB of scratch for z

  enc_kernel<<<256, 256, 0, stream>>>(x, We1, be1, We2, be2, zws);
  dec_kernel<<<256, 256, 0, stream>>>(W1s, b1s, W2s, b2s, zws, out);
}

// Round 3
// 1018.825 us; speedup vs baseline: 1.1101x; 1.1101x over previous
//
#include <hip/hip_runtime.h>

#define B_SZ 2048
#define D_SZ 128
#define H_SZ 512

typedef _Float16 half8 __attribute__((ext_vector_type(8)));
typedef float floatx4 __attribute__((ext_vector_type(4)));
typedef unsigned int uint4v __attribute__((ext_vector_type(4)));

static __device__ __forceinline__ float tanh_fast(float x) {
  // tanh(x) = 1 - 2/(e^{2x}+1); exact identity, saturates correctly at +-inf
  float e = __expf(2.0f * x);
  return 1.0f - 2.0f * __builtin_amdgcn_rcpf(e + 1.0f);
}

// Split two f32 into fp16 hi + fp16 lo (RTZ), packed as u32 each.
// a ~= hi + lo to ~22 mantissa bits (residual a - hi is exact in f32).
static __device__ __forceinline__ void split_pair(float a, float b,
                                                  unsigned int& hi,
                                                  unsigned int& lo) {
  auto h = __builtin_amdgcn_cvt_pkrtz(a, b);     // __fp16 x2, elem0 = low 16b
  float ra = a - (float)h[0];
  float rb = b - (float)h[1];
  auto l = __builtin_amdgcn_cvt_pkrtz(ra, rb);
  hi = __builtin_bit_cast(unsigned int, h);
  lo = __builtin_bit_cast(unsigned int, l);
}

// ---------------- W2s fp32 -> (W2h, W2l) fp16 split, same [j][d][h] layout --
// Memory-bound one-shot: 33.5 MB read + 33.5 MB write.
__global__ __launch_bounds__(256) void split_w2_kernel(
    const float* __restrict__ W2s, unsigned int* __restrict__ W2h,
    unsigned int* __restrict__ W2l) {
  const int idx = blockIdx.x * 256 + threadIdx.x;  // one float4 = 2 fp16 pairs
  const float4 v = ((const float4*)W2s)[idx];
  unsigned int h0, l0, h1, l1;
  split_pair(v.x, v.y, h0, l0);
  split_pair(v.z, v.w, h1, l1);
  ((uint2*)W2h)[idx] = make_uint2(h0, h1);
  ((uint2*)W2l)[idx] = make_uint2(l0, l1);
}

// ---------------- Encoder: z[j][b] = tanh(leaky(x@We1^T+be1)@We2^T+be2)^T ---
// fp32 vector math; 256 blocks x 256 threads, 8 batch rows per block.
__global__ __launch_bounds__(256) void enc_kernel(
    const float* __restrict__ x, const float* __restrict__ We1,
    const float* __restrict__ be1, const float* __restrict__ We2,
    const float* __restrict__ be2, float* __restrict__ z) {
  __shared__ float xs[8][132];
  __shared__ float hs[8][516];
  const int t = threadIdx.x;
  const int b0 = blockIdx.x * 8;
  {
    int r = t >> 5, c4 = t & 31;
    float4 v = ((const float4*)(x + (size_t)(b0 + r) * D_SZ))[c4];
    xs[r][c4 * 4 + 0] = v.x; xs[r][c4 * 4 + 1] = v.y;
    xs[r][c4 * 4 + 2] = v.z; xs[r][c4 * 4 + 3] = v.w;
  }
  __syncthreads();
  for (int hb = 0; hb < 2; ++hb) {
    const int h = t + hb * 256;
    float acc[8];
    float bias = be1[h];
#pragma unroll
    for (int r = 0; r < 8; ++r) acc[r] = bias;
    const float4* wp = (const float4*)(We1 + (size_t)h * D_SZ);
    for (int k4 = 0; k4 < 32; ++k4) {
      float4 wv = wp[k4];
#pragma unroll
      for (int r = 0; r < 8; ++r) {
        acc[r] = fmaf(wv.x, xs[r][k4 * 4 + 0], acc[r]);
        acc[r] = fmaf(wv.y, xs[r][k4 * 4 + 1], acc[r]);
        acc[r] = fmaf(wv.z, xs[r][k4 * 4 + 2], acc[r]);
        acc[r] = fmaf(wv.w, xs[r][k4 * 4 + 3], acc[r]);
      }
    }
#pragma unroll
    for (int r = 0; r < 8; ++r) {
      float u = acc[r];
      hs[r][h] = fmaxf(u, 0.2f * u);   // leaky 0.2
    }
  }
  __syncthreads();
  {
    const int d = t & 127, rg = t >> 7;
    float acc[4];
    float bias = be2[d];
#pragma unroll
    for (int r = 0; r < 4; ++r) acc[r] = bias;
    const float4* wp = (const float4*)(We2 + (size_t)d * H_SZ);
    for (int k4 = 0; k4 < 128; ++k4) {
      float4 wv = wp[k4];
#pragma unroll
      for (int r = 0; r < 4; ++r) {
        int row = rg * 4 + r;
        acc[r] = fmaf(wv.x, hs[row][k4 * 4 + 0], acc[r]);
        acc[r] = fmaf(wv.y, hs[row][k4 * 4 + 1], acc[r]);
        acc[r] = fmaf(wv.z, hs[row][k4 * 4 + 2], acc[r]);
        acc[r] = fmaf(wv.w, hs[row][k4 * 4 + 3], acc[r]);
      }
    }
#pragma unroll
    for (int r = 0; r < 4; ++r) {
      z[(size_t)d * B_SZ + b0 + rg * 4 + r] = tanh_fast(acc[r]);
    }
  }
}

// ---------------- Decoder bank + cumsum + tanh -----------------------------
// out[j,b,d] = tanh( sum_{j'<=j} ( hid[j',b,:] . W2s[j',d,:] + b2s[j',d] ) )
// hid computed per-lane in registers directly in MFMA A-frag layout; B frags
// loaded straight from precomputed fp16 hi/lo arrays. NO LDS in the j-loop,
// NO barriers. Block tile 64b x 16d (4 waves, disjoint b). Grid 32x8 = 256.
// d-tile = blockIdx&7 -> same-d blocks share one XCD's L2 for the W2 stream.
__global__ __launch_bounds__(256, 1) void dec_kernel(
    const float* __restrict__ W1s, const float* __restrict__ b1s,
    const _Float16* __restrict__ W2h, const _Float16* __restrict__ W2l,
    const float* __restrict__ b2s, const float* __restrict__ z,
    float* __restrict__ out) {
  __shared__ float zsh[128 * 64];   // this block's z slice: [j][b], 32 KB
  const int t = threadIdx.x;
  const int bx = blockIdx.x;
  const int dt = bx & 7, bt = bx >> 3;
  const int b0 = bt * 64, d0 = dt * 16;

#pragma unroll
  for (int i = 0; i < 32; ++i) {
    int e = t + 256 * i;
    zsh[e] = z[(size_t)(e >> 6) * B_SZ + b0 + (e & 63)];
  }
  __syncthreads();   // the only barrier in the kernel

  const int lane = t & 63, w = t >> 6;
  const int quad = lane >> 4, l16 = lane & 15;

  floatx4 acc0 = {0.f, 0.f, 0.f, 0.f};   // ah*bh (cumsum carrier)
  floatx4 acc1 = {0.f, 0.f, 0.f, 0.f};   // ah*bl
  floatx4 acc2 = {0.f, 0.f, 0.f, 0.f};   // al*bh
  float bcum = 0.f;                      // running b2s cumsum for my d

  const int zoff = w * 16 + l16;                          // A row = my b
  const size_t w2off = (size_t)(d0 + l16) * H_SZ + quad * 8;
  const int koff = quad * 8;

  for (int j = 0; j < 128; ++j) {
    const float* w1r = W1s + (size_t)j * H_SZ + koff;
    const float* b1r = b1s + (size_t)j * H_SZ + koff;
    const _Float16* w2hr = W2h + (size_t)j * (D_SZ * H_SZ) + w2off;
    const _Float16* w2lr = W2l + (size_t)j * (D_SZ * H_SZ) + w2off;
    const float zv = zsh[j * 64 + zoff];

#pragma unroll
    for (int s = 0; s < 16; ++s) {
      const int o = s * 32;              // k stride per s-step
      float4 w1a = *(const float4*)(w1r + o);
      float4 w1b = *(const float4*)(w1r + o + 4);
      float4 b1a = *(const float4*)(b1r + o);
      float4 b1b = *(const float4*)(b1r + o + 4);
      half8 fbh = *(const half8*)(w2hr + o);
      half8 fbl = *(const half8*)(w2lr + o);

      float h0 = fmaf(zv, w1a.x, b1a.x), h1 = fmaf(zv, w1a.y, b1a.y);
      float h2 = fmaf(zv, w1a.z, b1a.z), h3 = fmaf(zv, w1a.w, b1a.w);
      float h4 = fmaf(zv, w1b.x, b1b.x), h5 = fmaf(zv, w1b.y, b1b.y);
      float h6 = fmaf(zv, w1b.z, b1b.z), h7 = fmaf(zv, w1b.w, b1b.w);
      h0 = fmaxf(h0, 0.2f * h0); h1 = fmaxf(h1, 0.2f * h1);
      h2 = fmaxf(h2, 0.2f * h2); h3 = fmaxf(h3, 0.2f * h3);
      h4 = fmaxf(h4, 0.2f * h4); h5 = fmaxf(h5, 0.2f * h5);
      h6 = fmaxf(h6, 0.2f * h6); h7 = fmaxf(h7, 0.2f * h7);

      unsigned int ah0, ah1, ah2, ah3, al0, al1, al2, al3;
      split_pair(h0, h1, ah0, al0);
      split_pair(h2, h3, ah1, al1);
      split_pair(h4, h5, ah2, al2);
      split_pair(h6, h7, ah3, al3);
      half8 fah = __builtin_bit_cast(half8, (uint4v){ah0, ah1, ah2, ah3});
      half8 fal = __builtin_bit_cast(half8, (uint4v){al0, al1, al2, al3});

      acc0 = __builtin_amdgcn_mfma_f32_16x16x32_f16(fah, fbh, acc0, 0, 0, 0);
      acc1 = __builtin_amdgcn_mfma_f32_16x16x32_f16(fah, fbl, acc1, 0, 0, 0);
      acc2 = __builtin_amdgcn_mfma_f32_16x16x32_f16(fal, fbh, acc2, 0, 0, 0);
    }

    bcum += b2s[j * D_SZ + d0 + l16];
    float* orow = out + ((size_t)j * B_SZ + b0 + w * 16 + quad * 4) * D_SZ +
                  d0 + l16;
#pragma unroll
    for (int r = 0; r < 4; ++r) {
      float sv = (acc0[r] + acc1[r]) + (acc2[r] + bcum);
      orow[(size_t)r * D_SZ] = tanh_fast(sv);
    }
  }
}

extern "C" void kernel_launch(void* const* d_in, const int* in_sizes, int n_in,
                              void* d_out, int out_size, void* d_ws,
                              size_t ws_size, hipStream_t stream) {
  (void)in_sizes; (void)n_in; (void)out_size; (void)ws_size;
  const float* x   = (const float*)d_in[0];
  const float* We1 = (const float*)d_in[1];
  const float* be1 = (const float*)d_in[2];
  const float* We2 = (const float*)d_in[3];
  const float* be2 = (const float*)d_in[4];
  const float* W1s = (const float*)d_in[5];
  const float* b1s = (const float*)d_in[6];
  const float* W2s = (const float*)d_in[7];
  const float* b2s = (const float*)d_in[8];
  float* out = (float*)d_out;

  // ws layout: z (1 MB) | W2h fp16 (16 MB) | W2l fp16 (16 MB)  -> ~33 MiB
  float* zws = (float*)d_ws;
  _Float16* W2h = (_Float16*)((char*)d_ws + (1u << 20));
  _Float16* W2l = (_Float16*)((char*)d_ws + (1u << 20) + (1u << 24));

  split_w2_kernel<<<8192, 256, 0, stream>>>(W2s, (unsigned int*)W2h,
                                            (unsigned int*)W2l);
  enc_kernel<<<256, 256, 0, stream>>>(x, We1, be1, We2, be2, zws);
  dec_kernel<<<256, 256, 0, stream>>>(W1s, b1s, W2h, W2l, b2s, zws, out);
}

// Round 4
// 915.095 us; speedup vs baseline: 1.2360x; 1.1134x over previous
//
#include <hip/hip_runtime.h>

#define B_SZ 2048
#define D_SZ 128
#define H_SZ 512
#define JC 32   // j-chunk length (4 chunks)

typedef _Float16 half8 __attribute__((ext_vector_type(8)));
typedef float floatx4 __attribute__((ext_vector_type(4)));
typedef unsigned int uint4v __attribute__((ext_vector_type(4)));

static __device__ __forceinline__ float tanh_fast(float x) {
  float e = __expf(2.0f * x);
  return 1.0f - 2.0f * __builtin_amdgcn_rcpf(e + 1.0f);
}

// Split two f32 into fp16 hi + fp16 lo (RTZ), packed as u32 each.
static __device__ __forceinline__ void split_pair(float a, float b,
                                                  unsigned int& hi,
                                                  unsigned int& lo) {
  auto h = __builtin_amdgcn_cvt_pkrtz(a, b);
  float ra = a - (float)h[0];
  float rb = b - (float)h[1];
  auto l = __builtin_amdgcn_cvt_pkrtz(ra, rb);
  hi = __builtin_bit_cast(unsigned int, h);
  lo = __builtin_bit_cast(unsigned int, l);
}

// ---------------- W2s fp32 -> (W2h, W2l) fp16 split ------------------------
__global__ __launch_bounds__(256) void split_w2_kernel(
    const float* __restrict__ W2s, unsigned int* __restrict__ W2h,
    unsigned int* __restrict__ W2l) {
  const int idx = blockIdx.x * 256 + threadIdx.x;
  const float4 v = ((const float4*)W2s)[idx];
  unsigned int h0, l0, h1, l1;
  split_pair(v.x, v.y, h0, l0);
  split_pair(v.z, v.w, h1, l1);
  ((uint2*)W2h)[idx] = make_uint2(h0, h1);
  ((uint2*)W2l)[idx] = make_uint2(l0, l1);
}

// ---------------- Encoder (fp32 vector; fast enough) -----------------------
__global__ __launch_bounds__(256) void enc_kernel(
    const float* __restrict__ x, const float* __restrict__ We1,
    const float* __restrict__ be1, const float* __restrict__ We2,
    const float* __restrict__ be2, float* __restrict__ z) {
  __shared__ float xs[8][132];
  __shared__ float hs[8][516];
  const int t = threadIdx.x;
  const int b0 = blockIdx.x * 8;
  {
    int r = t >> 5, c4 = t & 31;
    float4 v = ((const float4*)(x + (size_t)(b0 + r) * D_SZ))[c4];
    xs[r][c4 * 4 + 0] = v.x; xs[r][c4 * 4 + 1] = v.y;
    xs[r][c4 * 4 + 2] = v.z; xs[r][c4 * 4 + 3] = v.w;
  }
  __syncthreads();
  for (int hb = 0; hb < 2; ++hb) {
    const int h = t + hb * 256;
    float acc[8];
    float bias = be1[h];
#pragma unroll
    for (int r = 0; r < 8; ++r) acc[r] = bias;
    const float4* wp = (const float4*)(We1 + (size_t)h * D_SZ);
    for (int k4 = 0; k4 < 32; ++k4) {
      float4 wv = wp[k4];
#pragma unroll
      for (int r = 0; r < 8; ++r) {
        acc[r] = fmaf(wv.x, xs[r][k4 * 4 + 0], acc[r]);
        acc[r] = fmaf(wv.y, xs[r][k4 * 4 + 1], acc[r]);
        acc[r] = fmaf(wv.z, xs[r][k4 * 4 + 2], acc[r]);
        acc[r] = fmaf(wv.w, xs[r][k4 * 4 + 3], acc[r]);
      }
    }
#pragma unroll
    for (int r = 0; r < 8; ++r) {
      float u = acc[r];
      hs[r][h] = fmaxf(u, 0.2f * u);
    }
  }
  __syncthreads();
  {
    const int d = t & 127, rg = t >> 7;
    float acc[4];
    float bias = be2[d];
#pragma unroll
    for (int r = 0; r < 4; ++r) acc[r] = bias;
    const float4* wp = (const float4*)(We2 + (size_t)d * H_SZ);
    for (int k4 = 0; k4 < 128; ++k4) {
      float4 wv = wp[k4];
#pragma unroll
      for (int r = 0; r < 4; ++r) {
        int row = rg * 4 + r;
        acc[r] = fmaf(wv.x, hs[row][k4 * 4 + 0], acc[r]);
        acc[r] = fmaf(wv.y, hs[row][k4 * 4 + 1], acc[r]);
        acc[r] = fmaf(wv.z, hs[row][k4 * 4 + 2], acc[r]);
        acc[r] = fmaf(wv.w, hs[row][k4 * 4 + 3], acc[r]);
      }
    }
#pragma unroll
    for (int r = 0; r < 4; ++r) {
      z[(size_t)d * B_SZ + b0 + rg * 4 + r] = tanh_fast(acc[r]);
    }
  }
}

// ---------------- Phase 1: per-j-chunk local prefix sums --------------------
// Wave tile 16b x 32d (2 B-cols, 6 accs). Block = 4 waves stacked in b
// (64b x 32d x 32j). Grid = 32 bt x 4 jc x 4 dt = 512 blocks -> 8 waves/CU.
// Chunk 0 writes final tanh; chunks 1-3 write raw partials + totals T[c].
__global__ __launch_bounds__(256, 2) void dec_kernel(
    const float* __restrict__ W1s, const float* __restrict__ b1s,
    const _Float16* __restrict__ W2h, const _Float16* __restrict__ W2l,
    const float* __restrict__ b2s, const float* __restrict__ z,
    float* __restrict__ out, float* __restrict__ T) {
  __shared__ float zsh[JC * 64];
  const int t = threadIdx.x;
  const int bx = blockIdx.x;
  const int bt = bx >> 4;
  const int jc = (bx >> 2) & 3;   // (jc,dt) in low bits -> XCD spread
  const int dt = bx & 3;
  const int b0 = bt * 64, d0 = dt * 32, j0 = jc * JC;

#pragma unroll
  for (int i = 0; i < 8; ++i) {
    int e = t + 256 * i;
    zsh[e] = z[(size_t)(j0 + (e >> 6)) * B_SZ + b0 + (e & 63)];
  }
  __syncthreads();   // only barrier

  const int lane = t & 63, w = t >> 6;
  const int quad = lane >> 4, l16 = lane & 15;

  floatx4 acc00 = {0.f,0.f,0.f,0.f}, acc01 = {0.f,0.f,0.f,0.f},
          acc02 = {0.f,0.f,0.f,0.f};                 // d-col 0: hh, hl, lh
  floatx4 acc10 = {0.f,0.f,0.f,0.f}, acc11 = {0.f,0.f,0.f,0.f},
          acc12 = {0.f,0.f,0.f,0.f};                 // d-col 1
  float bc0 = 0.f, bc1 = 0.f;

  const int zrow = w * 16 + l16;
  const int koff = quad * 8;
  const size_t w2base = (size_t)(d0 + l16) * H_SZ + koff;

  for (int jj = 0; jj < JC; ++jj) {
    const int j = j0 + jj;
    const float* w1r = W1s + (size_t)j * H_SZ + koff;
    const float* b1r = b1s + (size_t)j * H_SZ + koff;
    const _Float16* w2h0 = W2h + (size_t)j * (D_SZ * H_SZ) + w2base;
    const _Float16* w2l0 = W2l + (size_t)j * (D_SZ * H_SZ) + w2base;
    const float zv = zsh[jj * 64 + zrow];

#pragma unroll
    for (int s = 0; s < 16; ++s) {
      const int o = s * 32;
      float4 w1a = *(const float4*)(w1r + o);
      float4 w1b = *(const float4*)(w1r + o + 4);
      float4 b1a = *(const float4*)(b1r + o);
      float4 b1b = *(const float4*)(b1r + o + 4);
      half8 fb0h = *(const half8*)(w2h0 + o);
      half8 fb0l = *(const half8*)(w2l0 + o);
      half8 fb1h = *(const half8*)(w2h0 + 16 * H_SZ + o);
      half8 fb1l = *(const half8*)(w2l0 + 16 * H_SZ + o);

      float h0 = fmaf(zv, w1a.x, b1a.x), h1 = fmaf(zv, w1a.y, b1a.y);
      float h2 = fmaf(zv, w1a.z, b1a.z), h3 = fmaf(zv, w1a.w, b1a.w);
      float h4 = fmaf(zv, w1b.x, b1b.x), h5 = fmaf(zv, w1b.y, b1b.y);
      float h6 = fmaf(zv, w1b.z, b1b.z), h7 = fmaf(zv, w1b.w, b1b.w);
      h0 = fmaxf(h0, 0.2f * h0); h1 = fmaxf(h1, 0.2f * h1);
      h2 = fmaxf(h2, 0.2f * h2); h3 = fmaxf(h3, 0.2f * h3);
      h4 = fmaxf(h4, 0.2f * h4); h5 = fmaxf(h5, 0.2f * h5);
      h6 = fmaxf(h6, 0.2f * h6); h7 = fmaxf(h7, 0.2f * h7);

      unsigned int ah0, ah1, ah2, ah3, al0, al1, al2, al3;
      split_pair(h0, h1, ah0, al0);
      split_pair(h2, h3, ah1, al1);
      split_pair(h4, h5, ah2, al2);
      split_pair(h6, h7, ah3, al3);
      half8 fah = __builtin_bit_cast(half8, (uint4v){ah0, ah1, ah2, ah3});
      half8 fal = __builtin_bit_cast(half8, (uint4v){al0, al1, al2, al3});

      acc00 = __builtin_amdgcn_mfma_f32_16x16x32_f16(fah, fb0h, acc00, 0, 0, 0);
      acc01 = __builtin_amdgcn_mfma_f32_16x16x32_f16(fah, fb0l, acc01, 0, 0, 0);
      acc02 = __builtin_amdgcn_mfma_f32_16x16x32_f16(fal, fb0h, acc02, 0, 0, 0);
      acc10 = __builtin_amdgcn_mfma_f32_16x16x32_f16(fah, fb1h, acc10, 0, 0, 0);
      acc11 = __builtin_amdgcn_mfma_f32_16x16x32_f16(fah, fb1l, acc11, 0, 0, 0);
      acc12 = __builtin_amdgcn_mfma_f32_16x16x32_f16(fal, fb1h, acc12, 0, 0, 0);
    }

    bc0 += b2s[j * D_SZ + d0 + l16];
    bc1 += b2s[j * D_SZ + d0 + 16 + l16];

    float* ob = out + ((size_t)j * B_SZ + b0 + w * 16 + quad * 4) * D_SZ + d0;
    if (jc == 0) {
#pragma unroll
      for (int r = 0; r < 4; ++r) {
        float s0 = (acc00[r] + acc01[r]) + (acc02[r] + bc0);
        float s1 = (acc10[r] + acc11[r]) + (acc12[r] + bc1);
        ob[(size_t)r * D_SZ + l16] = tanh_fast(s0);
        ob[(size_t)r * D_SZ + 16 + l16] = tanh_fast(s1);
      }
    } else {
#pragma unroll
      for (int r = 0; r < 4; ++r) {
        float s0 = (acc00[r] + acc01[r]) + (acc02[r] + bc0);
        float s1 = (acc10[r] + acc11[r]) + (acc12[r] + bc1);
        ob[(size_t)r * D_SZ + l16] = s0;
        ob[(size_t)r * D_SZ + 16 + l16] = s1;
      }
    }
  }

  if (jc < 3) {   // chunk totals for phase-2 carries
    float* Tc = T + (size_t)jc * (B_SZ * D_SZ) +
                (size_t)(b0 + w * 16 + quad * 4) * D_SZ + d0;
#pragma unroll
    for (int r = 0; r < 4; ++r) {
      Tc[(size_t)r * D_SZ + l16] = (acc00[r] + acc01[r]) + (acc02[r] + bc0);
      Tc[(size_t)r * D_SZ + 16 + l16] = (acc10[r] + acc11[r]) + (acc12[r] + bc1);
    }
  }
}

// ---------------- Phase 2: carry fixup + tanh for j >= JC -------------------
__global__ __launch_bounds__(256) void fixup_kernel(
    const float* __restrict__ T, float* __restrict__ out) {
  const int idx = blockIdx.x * 256 + threadIdx.x;
  const int d4 = idx & 31;          // float4 index in d
  const int row = idx >> 5;
  const int b = row & (B_SZ - 1);
  const int jp = row >> 11;         // 0..95
  const int j = JC + jp;
  const int c = jp >> 5;            // 0,1,2 -> needs T0..Tc
  const size_t tix = (size_t)b * (D_SZ / 4) + d4;
  const float4* T4 = (const float4*)T;
  float4 carry = T4[tix];           // T0 always needed
  if (c >= 1) {
    float4 t1 = T4[(size_t)(B_SZ * D_SZ / 4) + tix];
    carry.x += t1.x; carry.y += t1.y; carry.z += t1.z; carry.w += t1.w;
  }
  if (c >= 2) {
    float4 t2 = T4[(size_t)(2 * (B_SZ * D_SZ / 4)) + tix];
    carry.x += t2.x; carry.y += t2.y; carry.z += t2.z; carry.w += t2.w;
  }
  float4* O4 = (float4*)out;
  const size_t oix = ((size_t)j * B_SZ + b) * (D_SZ / 4) + d4;
  float4 s = O4[oix];
  s.x = tanh_fast(s.x + carry.x);
  s.y = tanh_fast(s.y + carry.y);
  s.z = tanh_fast(s.z + carry.z);
  s.w = tanh_fast(s.w + carry.w);
  O4[oix] = s;
}

extern "C" void kernel_launch(void* const* d_in, const int* in_sizes, int n_in,
                              void* d_out, int out_size, void* d_ws,
                              size_t ws_size, hipStream_t stream) {
  (void)in_sizes; (void)n_in; (void)out_size; (void)ws_size;
  const float* x   = (const float*)d_in[0];
  const float* We1 = (const float*)d_in[1];
  const float* be1 = (const float*)d_in[2];
  const float* We2 = (const float*)d_in[3];
  const float* be2 = (const float*)d_in[4];
  const float* W1s = (const float*)d_in[5];
  const float* b1s = (const float*)d_in[6];
  const float* W2s = (const float*)d_in[7];
  const float* b2s = (const float*)d_in[8];
  float* out = (float*)d_out;

  // ws: z 1MB | W2h 16MB | W2l 16MB | T 3MB  -> 36 MiB
  float* zws = (float*)d_ws;
  _Float16* W2h = (_Float16*)((char*)d_ws + (1u << 20));
  _Float16* W2l = (_Float16*)((char*)d_ws + (1u << 20) + (1u << 24));
  float* T = (float*)((char*)d_ws + (1u << 20) + (2u << 24));

  split_w2_kernel<<<8192, 256, 0, stream>>>(W2s, (unsigned int*)W2h,
                                            (unsigned int*)W2l);
  enc_kernel<<<256, 256, 0, stream>>>(x, We1, be1, We2, be2, zws);
  dec_kernel<<<512, 256, 0, stream>>>(W1s, b1s, W2h, W2l, b2s, zws, out, T);
  fixup_kernel<<<24576, 256, 0, stream>>>(T, out);
}

// Round 5
// 834.448 us; speedup vs baseline: 1.3554x; 1.0966x over previous
//
#include <hip/hip_runtime.h>

#define B_SZ 2048
#define D_SZ 128
#define H_SZ 512
#define JC 8      // j-chunk length
#define NCH 16    // number of j-chunks
#define CPG 3     // fixup: chunks per thread-group
#define NGRP 5    // fixup: thread groups (1 + 15/CPG)

typedef _Float16 half8 __attribute__((ext_vector_type(8)));
typedef float floatx4 __attribute__((ext_vector_type(4)));
typedef unsigned int uint4v __attribute__((ext_vector_type(4)));

static __device__ __forceinline__ float tanh_fast(float x) {
  float e = __expf(2.0f * x);
  return 1.0f - 2.0f * __builtin_amdgcn_rcpf(e + 1.0f);
}

static __device__ __forceinline__ void split_pair(float a, float b,
                                                  unsigned int& hi,
                                                  unsigned int& lo) {
  auto h = __builtin_amdgcn_cvt_pkrtz(a, b);
  float ra = a - (float)h[0];
  float rb = b - (float)h[1];
  auto l = __builtin_amdgcn_cvt_pkrtz(ra, rb);
  hi = __builtin_bit_cast(unsigned int, h);
  lo = __builtin_bit_cast(unsigned int, l);
}

// ---------------- W2s fp32 -> (W2h, W2l) fp16 split ------------------------
__global__ __launch_bounds__(256) void split_w2_kernel(
    const float* __restrict__ W2s, unsigned int* __restrict__ W2h,
    unsigned int* __restrict__ W2l) {
  const int idx = blockIdx.x * 256 + threadIdx.x;
  const float4 v = ((const float4*)W2s)[idx];
  unsigned int h0, l0, h1, l1;
  split_pair(v.x, v.y, h0, l0);
  split_pair(v.z, v.w, h1, l1);
  ((uint2*)W2h)[idx] = make_uint2(h0, h1);
  ((uint2*)W2l)[idx] = make_uint2(l0, l1);
}

// ---------------- Encoder (fp32 vector) ------------------------------------
__global__ __launch_bounds__(256) void enc_kernel(
    const float* __restrict__ x, const float* __restrict__ We1,
    const float* __restrict__ be1, const float* __restrict__ We2,
    const float* __restrict__ be2, float* __restrict__ z) {
  __shared__ float xs[8][132];
  __shared__ float hs[8][516];
  const int t = threadIdx.x;
  const int b0 = blockIdx.x * 8;
  {
    int r = t >> 5, c4 = t & 31;
    float4 v = ((const float4*)(x + (size_t)(b0 + r) * D_SZ))[c4];
    xs[r][c4 * 4 + 0] = v.x; xs[r][c4 * 4 + 1] = v.y;
    xs[r][c4 * 4 + 2] = v.z; xs[r][c4 * 4 + 3] = v.w;
  }
  __syncthreads();
  for (int hb = 0; hb < 2; ++hb) {
    const int h = t + hb * 256;
    float acc[8];
    float bias = be1[h];
#pragma unroll
    for (int r = 0; r < 8; ++r) acc[r] = bias;
    const float4* wp = (const float4*)(We1 + (size_t)h * D_SZ);
    for (int k4 = 0; k4 < 32; ++k4) {
      float4 wv = wp[k4];
#pragma unroll
      for (int r = 0; r < 8; ++r) {
        acc[r] = fmaf(wv.x, xs[r][k4 * 4 + 0], acc[r]);
        acc[r] = fmaf(wv.y, xs[r][k4 * 4 + 1], acc[r]);
        acc[r] = fmaf(wv.z, xs[r][k4 * 4 + 2], acc[r]);
        acc[r] = fmaf(wv.w, xs[r][k4 * 4 + 3], acc[r]);
      }
    }
#pragma unroll
    for (int r = 0; r < 8; ++r) {
      float u = acc[r];
      hs[r][h] = fmaxf(u, 0.2f * u);
    }
  }
  __syncthreads();
  {
    const int d = t & 127, rg = t >> 7;
    float acc[4];
    float bias = be2[d];
#pragma unroll
    for (int r = 0; r < 4; ++r) acc[r] = bias;
    const float4* wp = (const float4*)(We2 + (size_t)d * H_SZ);
    for (int k4 = 0; k4 < 128; ++k4) {
      float4 wv = wp[k4];
#pragma unroll
      for (int r = 0; r < 4; ++r) {
        int row = rg * 4 + r;
        acc[r] = fmaf(wv.x, hs[row][k4 * 4 + 0], acc[r]);
        acc[r] = fmaf(wv.y, hs[row][k4 * 4 + 1], acc[r]);
        acc[r] = fmaf(wv.z, hs[row][k4 * 4 + 2], acc[r]);
        acc[r] = fmaf(wv.w, hs[row][k4 * 4 + 3], acc[r]);
      }
    }
#pragma unroll
    for (int r = 0; r < 4; ++r) {
      z[(size_t)d * B_SZ + b0 + rg * 4 + r] = tanh_fast(acc[r]);
    }
  }
}

// ---------------- Phase 1: per-j-chunk local prefix sums --------------------
// Wave tile 16b x 32d (6 accs). Block 64b x 32d x 8j. Grid = 2048 blocks:
// low 6 bits = cohort (jc*4+dt) so the 32 bt-blocks sharing one 512 KB W2
// slice land on one XCD's L2; 8 blocks/CU -> 32 waves/CU for latency hiding.
__global__ __launch_bounds__(256, 8) void dec_kernel(
    const float* __restrict__ W1s, const float* __restrict__ b1s,
    const _Float16* __restrict__ W2h, const _Float16* __restrict__ W2l,
    const float* __restrict__ b2s, const float* __restrict__ z,
    float* __restrict__ out, float* __restrict__ T) {
  __shared__ float zsh[JC * 64];
  const int t = threadIdx.x;
  const int bx = blockIdx.x;
  const int cohort = bx & 63;
  const int dt = cohort & 3;
  const int jc = cohort >> 2;      // 0..15
  const int bt = bx >> 6;          // 0..31
  const int b0 = bt * 64, d0 = dt * 32, j0 = jc * JC;

#pragma unroll
  for (int i = 0; i < 2; ++i) {
    int e = t + 256 * i;
    zsh[e] = z[(size_t)(j0 + (e >> 6)) * B_SZ + b0 + (e & 63)];
  }
  __syncthreads();   // only barrier

  const int lane = t & 63, w = t >> 6;
  const int quad = lane >> 4, l16 = lane & 15;

  floatx4 acc00 = {0.f,0.f,0.f,0.f}, acc01 = {0.f,0.f,0.f,0.f},
          acc02 = {0.f,0.f,0.f,0.f};
  floatx4 acc10 = {0.f,0.f,0.f,0.f}, acc11 = {0.f,0.f,0.f,0.f},
          acc12 = {0.f,0.f,0.f,0.f};
  float bc0 = 0.f, bc1 = 0.f;

  const int zrow = w * 16 + l16;
  const int koff = quad * 8;
  const size_t w2base = (size_t)(d0 + l16) * H_SZ + koff;

  for (int jj = 0; jj < JC; ++jj) {
    const int j = j0 + jj;
    const float* w1r = W1s + (size_t)j * H_SZ + koff;
    const float* b1r = b1s + (size_t)j * H_SZ + koff;
    const _Float16* w2h0 = W2h + (size_t)j * (D_SZ * H_SZ) + w2base;
    const _Float16* w2l0 = W2l + (size_t)j * (D_SZ * H_SZ) + w2base;
    const float zv = zsh[jj * 64 + zrow];

#pragma unroll
    for (int s = 0; s < 16; ++s) {
      const int o = s * 32;
      float4 w1a = *(const float4*)(w1r + o);
      float4 w1b = *(const float4*)(w1r + o + 4);
      float4 b1a = *(const float4*)(b1r + o);
      float4 b1b = *(const float4*)(b1r + o + 4);
      half8 fb0h = *(const half8*)(w2h0 + o);
      half8 fb0l = *(const half8*)(w2l0 + o);
      half8 fb1h = *(const half8*)(w2h0 + 16 * H_SZ + o);
      half8 fb1l = *(const half8*)(w2l0 + 16 * H_SZ + o);

      float h0 = fmaf(zv, w1a.x, b1a.x), h1 = fmaf(zv, w1a.y, b1a.y);
      float h2 = fmaf(zv, w1a.z, b1a.z), h3 = fmaf(zv, w1a.w, b1a.w);
      float h4 = fmaf(zv, w1b.x, b1b.x), h5 = fmaf(zv, w1b.y, b1b.y);
      float h6 = fmaf(zv, w1b.z, b1b.z), h7 = fmaf(zv, w1b.w, b1b.w);
      h0 = fmaxf(h0, 0.2f * h0); h1 = fmaxf(h1, 0.2f * h1);
      h2 = fmaxf(h2, 0.2f * h2); h3 = fmaxf(h3, 0.2f * h3);
      h4 = fmaxf(h4, 0.2f * h4); h5 = fmaxf(h5, 0.2f * h5);
      h6 = fmaxf(h6, 0.2f * h6); h7 = fmaxf(h7, 0.2f * h7);

      unsigned int ah0, ah1, ah2, ah3, al0, al1, al2, al3;
      split_pair(h0, h1, ah0, al0);
      split_pair(h2, h3, ah1, al1);
      split_pair(h4, h5, ah2, al2);
      split_pair(h6, h7, ah3, al3);
      half8 fah = __builtin_bit_cast(half8, (uint4v){ah0, ah1, ah2, ah3});
      half8 fal = __builtin_bit_cast(half8, (uint4v){al0, al1, al2, al3});

      acc00 = __builtin_amdgcn_mfma_f32_16x16x32_f16(fah, fb0h, acc00, 0, 0, 0);
      acc01 = __builtin_amdgcn_mfma_f32_16x16x32_f16(fah, fb0l, acc01, 0, 0, 0);
      acc02 = __builtin_amdgcn_mfma_f32_16x16x32_f16(fal, fb0h, acc02, 0, 0, 0);
      acc10 = __builtin_amdgcn_mfma_f32_16x16x32_f16(fah, fb1h, acc10, 0, 0, 0);
      acc11 = __builtin_amdgcn_mfma_f32_16x16x32_f16(fah, fb1l, acc11, 0, 0, 0);
      acc12 = __builtin_amdgcn_mfma_f32_16x16x32_f16(fal, fb1h, acc12, 0, 0, 0);
    }

    bc0 += b2s[j * D_SZ + d0 + l16];
    bc1 += b2s[j * D_SZ + d0 + 16 + l16];

    float* ob = out + ((size_t)j * B_SZ + b0 + w * 16 + quad * 4) * D_SZ + d0;
    if (jc == 0) {
#pragma unroll
      for (int r = 0; r < 4; ++r) {
        float s0 = (acc00[r] + acc01[r]) + (acc02[r] + bc0);
        float s1 = (acc10[r] + acc11[r]) + (acc12[r] + bc1);
        ob[(size_t)r * D_SZ + l16] = tanh_fast(s0);
        ob[(size_t)r * D_SZ + 16 + l16] = tanh_fast(s1);
      }
    } else {
#pragma unroll
      for (int r = 0; r < 4; ++r) {
        float s0 = (acc00[r] + acc01[r]) + (acc02[r] + bc0);
        float s1 = (acc10[r] + acc11[r]) + (acc12[r] + bc1);
        ob[(size_t)r * D_SZ + l16] = s0;
        ob[(size_t)r * D_SZ + 16 + l16] = s1;
      }
    }
  }

  if (jc < NCH - 1) {   // chunk totals for phase-2 carries
    float* Tc = T + (size_t)jc * (B_SZ * D_SZ) +
                (size_t)(b0 + w * 16 + quad * 4) * D_SZ + d0;
#pragma unroll
    for (int r = 0; r < 4; ++r) {
      Tc[(size_t)r * D_SZ + l16] = (acc00[r] + acc01[r]) + (acc02[r] + bc0);
      Tc[(size_t)r * D_SZ + 16 + l16] = (acc10[r] + acc11[r]) + (acc12[r] + bc1);
    }
  }
}

// ---------------- Phase 2: carry fixup + tanh for j >= JC -------------------
// Thread owns (b, d4) and walks CPG chunks with a running carry.
__global__ __launch_bounds__(256) void fixup_kernel(
    const float* __restrict__ T, float* __restrict__ out) {
  const int idx = blockIdx.x * 256 + threadIdx.x;
  const int d4 = idx & 31;
  const int b = (idx >> 5) & (B_SZ - 1);
  const int q = idx >> 16;                 // 0..NGRP-1
  const size_t stride = B_SZ * (D_SZ / 4);
  const size_t tix = (size_t)b * (D_SZ / 4) + d4;
  const float4* T4 = (const float4*)T;
  float4* O4 = (float4*)out;

  const int c0 = 1 + q * CPG;
  float4 carry = make_float4(0.f, 0.f, 0.f, 0.f);
  for (int c = 0; c < c0; ++c) {
    float4 tv = T4[(size_t)c * stride + tix];
    carry.x += tv.x; carry.y += tv.y; carry.z += tv.z; carry.w += tv.w;
  }
#pragma unroll
  for (int cc = 0; cc < CPG; ++cc) {
    const int c = c0 + cc;
    if (cc > 0) {
      float4 tv = T4[(size_t)(c - 1) * stride + tix];
      carry.x += tv.x; carry.y += tv.y; carry.z += tv.z; carry.w += tv.w;
    }
#pragma unroll
    for (int jj = 0; jj < JC; ++jj) {
      const int j = c * JC + jj;
      const size_t oix = ((size_t)j * B_SZ + b) * (D_SZ / 4) + d4;
      float4 s = O4[oix];
      s.x = tanh_fast(s.x + carry.x);
      s.y = tanh_fast(s.y + carry.y);
      s.z = tanh_fast(s.z + carry.z);
      s.w = tanh_fast(s.w + carry.w);
      O4[oix] = s;
    }
  }
}

extern "C" void kernel_launch(void* const* d_in, const int* in_sizes, int n_in,
                              void* d_out, int out_size, void* d_ws,
                              size_t ws_size, hipStream_t stream) {
  (void)in_sizes; (void)n_in; (void)out_size; (void)ws_size;
  const float* x   = (const float*)d_in[0];
  const float* We1 = (const float*)d_in[1];
  const float* be1 = (const float*)d_in[2];
  const float* We2 = (const float*)d_in[3];
  const float* be2 = (const float*)d_in[4];
  const float* W1s = (const float*)d_in[5];
  const float* b1s = (const float*)d_in[6];
  const float* W2s = (const float*)d_in[7];
  const float* b2s = (const float*)d_in[8];
  float* out = (float*)d_out;

  // ws: z 1MB | W2h 16MB | W2l 16MB | T 15MB  -> 48 MiB
  float* zws = (float*)d_ws;
  _Float16* W2h = (_Float16*)((char*)d_ws + (1u << 20));
  _Float16* W2l = (_Float16*)((char*)d_ws + (1u << 20) + (1u << 24));
  float* T = (float*)((char*)d_ws + (1u << 20) + (2u << 24));

  split_w2_kernel<<<8192, 256, 0, stream>>>(W2s, (unsigned int*)W2h,
                                            (unsigned int*)W2l);
  enc_kernel<<<256, 256, 0, stream>>>(x, We1, be1, We2, be2, zws);
  dec_kernel<<<2048, 256, 0, stream>>>(W1s, b1s, W2h, W2l, b2s, zws, out, T);
  fixup_kernel<<<NGRP * 256, 256, 0, stream>>>(T, out);
}

// Round 6
// 386.405 us; speedup vs baseline: 2.9271x; 2.1595x over previous
//
#include <hip/hip_runtime.h>

#define B_SZ 2048
#define D_SZ 128
#define H_SZ 512
#define JC 8      // j-chunk length
#define NCH 16    // number of j-chunks
#define CPG 3     // fixup: chunks per thread-group
#define NGRP 5    // fixup: thread groups (1 + 15/CPG)

typedef _Float16 half8 __attribute__((ext_vector_type(8)));
typedef float floatx4 __attribute__((ext_vector_type(4)));
typedef unsigned int uint4v __attribute__((ext_vector_type(4)));

static __device__ __forceinline__ float tanh_fast(float x) {
  float e = __expf(2.0f * x);
  return 1.0f - 2.0f * __builtin_amdgcn_rcpf(e + 1.0f);
}

static __device__ __forceinline__ void split_pair(float a, float b,
                                                  unsigned int& hi,
                                                  unsigned int& lo) {
  auto h = __builtin_amdgcn_cvt_pkrtz(a, b);
  float ra = a - (float)h[0];
  float rb = b - (float)h[1];
  auto l = __builtin_amdgcn_cvt_pkrtz(ra, rb);
  hi = __builtin_bit_cast(unsigned int, h);
  lo = __builtin_bit_cast(unsigned int, l);
}

// ---- W2s fp32 -> tiled fp16 hi/lo: W2t[j][dt][kg][dl][k8] -----------------
// (dt: 64-d slice, kg = k/8 octet-group, dl = d%64, k8 = k%8). A dec block's
// per-kstep B-frag is then 2 contiguous 256-B segments. Writes coalesced.
__global__ __launch_bounds__(256) void split_w2_kernel(
    const float* __restrict__ W2s, _Float16* __restrict__ W2h,
    _Float16* __restrict__ W2l) {
  const int idx = blockIdx.x * 256 + threadIdx.x;   // (j,dt,kg,dl)
  const int dl = idx & 63, kg = (idx >> 6) & 63, dtj = idx >> 12; // dtj=j*2+dt
  const int d = (dtj & 1) * 64 + dl, j = dtj >> 1;
  const float* src = W2s + ((size_t)j * D_SZ + d) * H_SZ + kg * 8;
  float4 a = *(const float4*)src;
  float4 b = *(const float4*)(src + 4);
  unsigned int h0, l0, h1, l1, h2, l2, h3, l3;
  split_pair(a.x, a.y, h0, l0); split_pair(a.z, a.w, h1, l1);
  split_pair(b.x, b.y, h2, l2); split_pair(b.z, b.w, h3, l3);
  ((uint4*)W2h)[idx] = make_uint4(h0, h1, h2, h3);   // idx*8 halves
  ((uint4*)W2l)[idx] = make_uint4(l0, l1, l2, l3);
}

// ---- Encoder (fp32 vector) -------------------------------------------------
__global__ __launch_bounds__(256) void enc_kernel(
    const float* __restrict__ x, const float* __restrict__ We1,
    const float* __restrict__ be1, const float* __restrict__ We2,
    const float* __restrict__ be2, float* __restrict__ z) {
  __shared__ float xs[8][132];
  __shared__ float hs[8][516];
  const int t = threadIdx.x;
  const int b0 = blockIdx.x * 8;
  {
    int r = t >> 5, c4 = t & 31;
    float4 v = ((const float4*)(x + (size_t)(b0 + r) * D_SZ))[c4];
    xs[r][c4 * 4 + 0] = v.x; xs[r][c4 * 4 + 1] = v.y;
    xs[r][c4 * 4 + 2] = v.z; xs[r][c4 * 4 + 3] = v.w;
  }
  __syncthreads();
  for (int hb = 0; hb < 2; ++hb) {
    const int h = t + hb * 256;
    float acc[8];
    float bias = be1[h];
#pragma unroll
    for (int r = 0; r < 8; ++r) acc[r] = bias;
    const float4* wp = (const float4*)(We1 + (size_t)h * D_SZ);
    for (int k4 = 0; k4 < 32; ++k4) {
      float4 wv = wp[k4];
#pragma unroll
      for (int r = 0; r < 8; ++r) {
        acc[r] = fmaf(wv.x, xs[r][k4 * 4 + 0], acc[r]);
        acc[r] = fmaf(wv.y, xs[r][k4 * 4 + 1], acc[r]);
        acc[r] = fmaf(wv.z, xs[r][k4 * 4 + 2], acc[r]);
        acc[r] = fmaf(wv.w, xs[r][k4 * 4 + 3], acc[r]);
      }
    }
#pragma unroll
    for (int r = 0; r < 8; ++r) {
      float u = acc[r];
      hs[r][h] = fmaxf(u, 0.2f * u);
    }
  }
  __syncthreads();
  {
    const int d = t & 127, rg = t >> 7;
    float acc[4];
    float bias = be2[d];
#pragma unroll
    for (int r = 0; r < 4; ++r) acc[r] = bias;
    const float4* wp = (const float4*)(We2 + (size_t)d * H_SZ);
    for (int k4 = 0; k4 < 128; ++k4) {
      float4 wv = wp[k4];
#pragma unroll
      for (int r = 0; r < 4; ++r) {
        int row = rg * 4 + r;
        acc[r] = fmaf(wv.x, hs[row][k4 * 4 + 0], acc[r]);
        acc[r] = fmaf(wv.y, hs[row][k4 * 4 + 1], acc[r]);
        acc[r] = fmaf(wv.z, hs[row][k4 * 4 + 2], acc[r]);
        acc[r] = fmaf(wv.w, hs[row][k4 * 4 + 3], acc[r]);
      }
    }
#pragma unroll
    for (int r = 0; r < 4; ++r) {
      z[(size_t)d * B_SZ + b0 + rg * 4 + r] = tanh_fast(acc[r]);
    }
  }
}

// ---- Phase 1: per-j-chunk local prefix sums --------------------------------
// Block 64b x 64d x 8j; 4 waves, wave tile 32b x 32d (2x2 16x16 frags).
// w1/b1/z/b2s staged to LDS once (1 barrier); A computed in-register per
// lane; B frags loaded直接 from tiled global fp16 (2x256B segments).
// Grid = 32 bt x (16 jc x 2 dt) = 1024 -> 4 blocks/CU, 4 waves/SIMD.
__global__ __launch_bounds__(256, 4) void dec_kernel(
    const float* __restrict__ W1s, const float* __restrict__ b1s,
    const _Float16* __restrict__ W2h, const _Float16* __restrict__ W2l,
    const float* __restrict__ b2s, const float* __restrict__ z,
    float* __restrict__ out, float* __restrict__ T) {
  __shared__ float w1L[JC][512];
  __shared__ float b1L[JC][512];
  __shared__ float zL[JC][64];
  __shared__ float b2L[JC][64];

  const int t = threadIdx.x, bx = blockIdx.x;
  const int cohort = bx & 31, bt = bx >> 5;   // cohort on one XCD (bx%8)
  const int dt = cohort & 1, jc = cohort >> 1;
  const int b0 = bt * 64, d0 = dt * 64, j0 = jc * JC;

#pragma unroll
  for (int i = 0; i < 4; ++i) {
    int g = t + 256 * i;                    // float4 granule 0..1023
    int jr = g >> 7, col = (g & 127) * 4;
    *(float4*)&w1L[jr][col] = *(const float4*)(W1s + (size_t)(j0 + jr) * H_SZ + col);
    *(float4*)&b1L[jr][col] = *(const float4*)(b1s + (size_t)(j0 + jr) * H_SZ + col);
  }
  if (t < 128) {
    int jr = t >> 4, col = (t & 15) * 4;
    *(float4*)&zL[jr][col]  = *(const float4*)(z   + (size_t)(j0 + jr) * B_SZ + b0 + col);
    *(float4*)&b2L[jr][col] = *(const float4*)(b2s + (size_t)(j0 + jr) * D_SZ + d0 + col);
  }
  __syncthreads();   // only barrier

  const int lane = t & 63;
  const int quad = lane >> 4, l16 = lane & 15;
  const int wb = (t >> 6) & 1, wd = t >> 7;
  const int brow0 = wb * 32 + l16;          // bf=0 local b-row (bf=1: +16)

  floatx4 acc[2][2][3];                     // [bf][df][pass: hh,hl,lh]
#pragma unroll
  for (int a = 0; a < 2; ++a)
#pragma unroll
    for (int b = 0; b < 2; ++b)
#pragma unroll
      for (int p = 0; p < 3; ++p) acc[a][b][p] = (floatx4){0.f, 0.f, 0.f, 0.f};
  float bc0 = 0.f, bc1 = 0.f;

  for (int jj = 0; jj < JC; ++jj) {
    const int j = j0 + jj;
    const size_t bbase = ((size_t)j * 2 + dt) * 32768 + (wd * 32 + l16) * 8;
    const float zv0 = zL[jj][brow0];
    const float zv1 = zL[jj][brow0 + 16];

#pragma unroll 2
    for (int ks = 0; ks < 16; ++ks) {
      const int ko = ks * 32 + quad * 8;
      // shared w1/b1 octet (LDS broadcast, same addr across 16 lanes)
      float4 wa = *(const float4*)&w1L[jj][ko];
      float4 wc = *(const float4*)&w1L[jj][ko + 4];
      float4 ba = *(const float4*)&b1L[jj][ko];
      float4 bb = *(const float4*)&b1L[jj][ko + 4];
      // B frags: tiled layout, kg = ks*4+quad page, 2x256B segments
      const size_t boff = bbase + (size_t)(ks * 4 + quad) * 512;
      half8 fb0h = *(const half8*)(W2h + boff);
      half8 fb0l = *(const half8*)(W2l + boff);
      half8 fb1h = *(const half8*)(W2h + boff + 128);
      half8 fb1l = *(const half8*)(W2l + boff + 128);

      // A frag bf=0 (rows wb*32+l16)
      float h0 = fmaf(zv0, wa.x, ba.x), h1 = fmaf(zv0, wa.y, ba.y);
      float h2 = fmaf(zv0, wa.z, ba.z), h3 = fmaf(zv0, wa.w, ba.w);
      float h4 = fmaf(zv0, wc.x, bb.x), h5 = fmaf(zv0, wc.y, bb.y);
      float h6 = fmaf(zv0, wc.z, bb.z), h7 = fmaf(zv0, wc.w, bb.w);
      h0 = fmaxf(h0, 0.2f * h0); h1 = fmaxf(h1, 0.2f * h1);
      h2 = fmaxf(h2, 0.2f * h2); h3 = fmaxf(h3, 0.2f * h3);
      h4 = fmaxf(h4, 0.2f * h4); h5 = fmaxf(h5, 0.2f * h5);
      h6 = fmaxf(h6, 0.2f * h6); h7 = fmaxf(h7, 0.2f * h7);
      unsigned int a0, a1, a2, a3, x0, x1, x2, x3;
      split_pair(h0, h1, a0, x0); split_pair(h2, h3, a1, x1);
      split_pair(h4, h5, a2, x2); split_pair(h6, h7, a3, x3);
      half8 fa0h = __builtin_bit_cast(half8, (uint4v){a0, a1, a2, a3});
      half8 fa0l = __builtin_bit_cast(half8, (uint4v){x0, x1, x2, x3});
      // A frag bf=1 (rows +16)
      h0 = fmaf(zv1, wa.x, ba.x); h1 = fmaf(zv1, wa.y, ba.y);
      h2 = fmaf(zv1, wa.z, ba.z); h3 = fmaf(zv1, wa.w, ba.w);
      h4 = fmaf(zv1, wc.x, bb.x); h5 = fmaf(zv1, wc.y, bb.y);
      h6 = fmaf(zv1, wc.z, bb.z); h7 = fmaf(zv1, wc.w, bb.w);
      h0 = fmaxf(h0, 0.2f * h0); h1 = fmaxf(h1, 0.2f * h1);
      h2 = fmaxf(h2, 0.2f * h2); h3 = fmaxf(h3, 0.2f * h3);
      h4 = fmaxf(h4, 0.2f * h4); h5 = fmaxf(h5, 0.2f * h5);
      h6 = fmaxf(h6, 0.2f * h6); h7 = fmaxf(h7, 0.2f * h7);
      split_pair(h0, h1, a0, x0); split_pair(h2, h3, a1, x1);
      split_pair(h4, h5, a2, x2); split_pair(h6, h7, a3, x3);
      half8 fa1h = __builtin_bit_cast(half8, (uint4v){a0, a1, a2, a3});
      half8 fa1l = __builtin_bit_cast(half8, (uint4v){x0, x1, x2, x3});

      acc[0][0][0] = __builtin_amdgcn_mfma_f32_16x16x32_f16(fa0h, fb0h, acc[0][0][0], 0, 0, 0);
      acc[0][0][1] = __builtin_amdgcn_mfma_f32_16x16x32_f16(fa0h, fb0l, acc[0][0][1], 0, 0, 0);
      acc[0][0][2] = __builtin_amdgcn_mfma_f32_16x16x32_f16(fa0l, fb0h, acc[0][0][2], 0, 0, 0);
      acc[0][1][0] = __builtin_amdgcn_mfma_f32_16x16x32_f16(fa0h, fb1h, acc[0][1][0], 0, 0, 0);
      acc[0][1][1] = __builtin_amdgcn_mfma_f32_16x16x32_f16(fa0h, fb1l, acc[0][1][1], 0, 0, 0);
      acc[0][1][2] = __builtin_amdgcn_mfma_f32_16x16x32_f16(fa0l, fb1h, acc[0][1][2], 0, 0, 0);
      acc[1][0][0] = __builtin_amdgcn_mfma_f32_16x16x32_f16(fa1h, fb0h, acc[1][0][0], 0, 0, 0);
      acc[1][0][1] = __builtin_amdgcn_mfma_f32_16x16x32_f16(fa1h, fb0l, acc[1][0][1], 0, 0, 0);
      acc[1][0][2] = __builtin_amdgcn_mfma_f32_16x16x32_f16(fa1l, fb0h, acc[1][0][2], 0, 0, 0);
      acc[1][1][0] = __builtin_amdgcn_mfma_f32_16x16x32_f16(fa1h, fb1h, acc[1][1][0], 0, 0, 0);
      acc[1][1][1] = __builtin_amdgcn_mfma_f32_16x16x32_f16(fa1h, fb1l, acc[1][1][1], 0, 0, 0);
      acc[1][1][2] = __builtin_amdgcn_mfma_f32_16x16x32_f16(fa1l, fb1h, acc[1][1][2], 0, 0, 0);
    }

    bc0 += b2L[jj][wd * 32 + l16];
    bc1 += b2L[jj][wd * 32 + 16 + l16];

    const int dcol = d0 + wd * 32 + l16;
    float* obase = out + (size_t)j * (B_SZ * D_SZ) + dcol;
#pragma unroll
    for (int bf = 0; bf < 2; ++bf) {
      const int brow = b0 + wb * 32 + bf * 16 + quad * 4;
      float* orow = obase + (size_t)brow * D_SZ;
#pragma unroll
      for (int r = 0; r < 4; ++r) {
        float s0 = (acc[bf][0][0][r] + acc[bf][0][1][r]) + (acc[bf][0][2][r] + bc0);
        float s1 = (acc[bf][1][0][r] + acc[bf][1][1][r]) + (acc[bf][1][2][r] + bc1);
        if (jc == 0) { s0 = tanh_fast(s0); s1 = tanh_fast(s1); }
        orow[(size_t)r * D_SZ] = s0;
        orow[(size_t)r * D_SZ + 16] = s1;
      }
    }
  }

  if (jc < NCH - 1) {   // chunk totals for phase-2 carries
    const int dcol = d0 + wd * 32 + l16;
    float* tbase = T + (size_t)jc * (B_SZ * D_SZ) + dcol;
#pragma unroll
    for (int bf = 0; bf < 2; ++bf) {
      const int brow = b0 + wb * 32 + bf * 16 + quad * 4;
      float* trow = tbase + (size_t)brow * D_SZ;
#pragma unroll
      for (int r = 0; r < 4; ++r) {
        trow[(size_t)r * D_SZ] =
            (acc[bf][0][0][r] + acc[bf][0][1][r]) + (acc[bf][0][2][r] + bc0);
        trow[(size_t)r * D_SZ + 16] =
            (acc[bf][1][0][r] + acc[bf][1][1][r]) + (acc[bf][1][2][r] + bc1);
      }
    }
  }
}

// ---- Phase 2: carry fixup + tanh for j >= JC -------------------------------
__global__ __launch_bounds__(256) void fixup_kernel(
    const float* __restrict__ T, float* __restrict__ out) {
  const int idx = blockIdx.x * 256 + threadIdx.x;
  const int d4 = idx & 31;
  const int b = (idx >> 5) & (B_SZ - 1);
  const int q = idx >> 16;                 // 0..NGRP-1
  const size_t stride = B_SZ * (D_SZ / 4);
  const size_t tix = (size_t)b * (D_SZ / 4) + d4;
  const float4* T4 = (const float4*)T;
  float4* O4 = (float4*)out;

  const int c0 = 1 + q * CPG;
  float4 carry = make_float4(0.f, 0.f, 0.f, 0.f);
  for (int c = 0; c < c0; ++c) {
    float4 tv = T4[(size_t)c * stride + tix];
    carry.x += tv.x; carry.y += tv.y; carry.z += tv.z; carry.w += tv.w;
  }
#pragma unroll
  for (int cc = 0; cc < CPG; ++cc) {
    const int c = c0 + cc;
    if (cc > 0) {
      float4 tv = T4[(size_t)(c - 1) * stride + tix];
      carry.x += tv.x; carry.y += tv.y; carry.z += tv.z; carry.w += tv.w;
    }
#pragma unroll
    for (int jj = 0; jj < JC; ++jj) {
      const int j = c * JC + jj;
      const size_t oix = ((size_t)j * B_SZ + b) * (D_SZ / 4) + d4;
      float4 s = O4[oix];
      s.x = tanh_fast(s.x + carry.x);
      s.y = tanh_fast(s.y + carry.y);
      s.z = tanh_fast(s.z + carry.z);
      s.w = tanh_fast(s.w + carry.w);
      O4[oix] = s;
    }
  }
}

extern "C" void kernel_launch(void* const* d_in, const int* in_sizes, int n_in,
                              void* d_out, int out_size, void* d_ws,
                              size_t ws_size, hipStream_t stream) {
  (void)in_sizes; (void)n_in; (void)out_size; (void)ws_size;
  const float* x   = (const float*)d_in[0];
  const float* We1 = (const float*)d_in[1];
  const float* be1 = (const float*)d_in[2];
  const float* We2 = (const float*)d_in[3];
  const float* be2 = (const float*)d_in[4];
  const float* W1s = (const float*)d_in[5];
  const float* b1s = (const float*)d_in[6];
  const float* W2s = (const float*)d_in[7];
  const float* b2s = (const float*)d_in[8];
  float* out = (float*)d_out;

  // ws: z 1MB | W2h 16MB | W2l 16MB | T 15MB  -> 48 MiB
  float* zws = (float*)d_ws;
  _Float16* W2h = (_Float16*)((char*)d_ws + (1u << 20));
  _Float16* W2l = (_Float16*)((char*)d_ws + (1u << 20) + (1u << 24));
  float* T = (float*)((char*)d_ws + (1u << 20) + (2u << 24));

  split_w2_kernel<<<4096, 256, 0, stream>>>(W2s, W2h, W2l);
  enc_kernel<<<256, 256, 0, stream>>>(x, We1, be1, We2, be2, zws);
  dec_kernel<<<1024, 256, 0, stream>>>(W1s, b1s, W2h, W2l, b2s, zws, out, T);
  fixup_kernel<<<NGRP * 256, 256, 0, stream>>>(T, out);
}